// Round 1
// baseline (125.152 us; speedup 1.0000x reference)
//
#include <hip/hip_runtime.h>
#include <hip/hip_bf16.h>

typedef short s8v  __attribute__((ext_vector_type(8)));
typedef float f32x4 __attribute__((ext_vector_type(4)));

// RNE float -> bf16 bits
__device__ __forceinline__ unsigned short f2bf(float f) {
  unsigned int b = __float_as_uint(f);
  b += 0x7fffu + ((b >> 16) & 1u);
  return (unsigned short)(b >> 16);
}

// ---------------- prep_w: Wa/Wb and Wproj into MFMA-fragment order ----------------
// wab  : [nt<4][kt<8][lane<64][j<8]  = bf16 W[(p=nt*16+(lane&15))][c=kt*32+8*(lane>>4)+j], p<32->Wa else Wb
// wfrag: [nt<8][kt<32][lane<64][j<8] = bf16 Wproj[z=nt*16+(lane&15)][korig], k'=kt*32+8*(lane>>4)+j,
//        c=k'&31, d=k'>>5, korig=c*32+d   (k' = d*32+c permutation)
__global__ __launch_bounds__(256) void prep_w_kernel(
    const float* __restrict__ Wa, const float* __restrict__ Wb,
    const float* __restrict__ Wproj,
    unsigned short* __restrict__ wab, unsigned short* __restrict__ wfrag) {
  int gid = blockIdx.x * 256 + threadIdx.x;
  if (gid < 16384) {
    int e = gid;
    int j = e & 7, lane = (e >> 3) & 63, kt = (e >> 9) & 7, nt = e >> 12;
    int p = nt * 16 + (lane & 15);
    int c = kt * 32 + ((lane >> 4) << 3) + j;
    float v = (p < 32) ? Wa[p * 256 + c] : Wb[(p - 32) * 256 + c];
    wab[e] = f2bf(v);
  } else {
    int e = gid - 16384;
    int j = e & 7, lane = (e >> 3) & 63, kt = (e >> 9) & 31, nt = e >> 14;
    int z = nt * 16 + (lane & 15);
    int kp = kt * 32 + ((lane >> 4) << 3) + j;
    int c = kp & 31, d = kp >> 5;
    wfrag[e] = f2bf(Wproj[z * 1024 + c * 32 + d]);
  }
}

// ---------------- kernel_a: LN + MFMA projection + fragment-order transpose ----------------
// block = (i, s-half): 768 blocks, 256 threads (4 waves).
// outputs afrag/bfrag: [rowblock rb<768][kt<4][lane<64][j<8] bf16,
//   element = a_t[rb*16+(lane&15)][s = kt*32 + 8*(lane>>4) + j],  a_t[(i*32+c)][s] = a[s,i,c]
#define XS 264   // x_lds row stride (halfwords), 528B: 16B-mult, bank-spread pad
#define OS 66    // o_lds row stride (floats)
__global__ __launch_bounds__(256) void kernel_a(
    const float* __restrict__ msa, const float* __restrict__ gamma, const float* __restrict__ beta,
    const unsigned short* __restrict__ wab,
    unsigned short* __restrict__ afrag, unsigned short* __restrict__ bfrag) {
  __shared__ unsigned short xs[64 * XS];   // normalized x, bf16 [64 local s][256 c]
  __shared__ float os[64 * OS];            // proj result fp32 [64 local s][64 p]
  const int i  = blockIdx.x >> 1;
  const int sh = blockIdx.x & 1;           // s-half: s in [sh*64, sh*64+64)
  const int tid = threadIdx.x;
  const int w = tid >> 6, lane = tid & 63;
  const int gq = lane >> 4, nlo = lane & 15;

  // per-lane fixed c-slice of gamma/beta
  const float4 g4  = *(const float4*)(gamma + lane * 4);
  const float4 be4 = *(const float4*)(beta  + lane * 4);

  // phase 1: LayerNorm, one row per wave per iter
  for (int it = 0; it < 16; ++it) {
    const int sl = it * 4 + w;
    const int s  = sh * 64 + sl;
    const float4 v = *(const float4*)(msa + (size_t)(s * 384 + i) * 256 + lane * 4);
    float sum = v.x + v.y + v.z + v.w;
    float sq  = fmaf(v.x, v.x, fmaf(v.y, v.y, fmaf(v.z, v.z, v.w * v.w)));
#pragma unroll
    for (int off = 32; off >= 1; off >>= 1) {
      sum += __shfl_xor(sum, off);
      sq  += __shfl_xor(sq,  off);
    }
    const float mu   = sum * (1.f / 256.f);
    const float var  = sq * (1.f / 256.f) - mu * mu;
    const float rstd = rsqrtf(var + 1e-5f);
    unsigned int lo = (unsigned int)f2bf((v.x - mu) * rstd * g4.x + be4.x)
                    | ((unsigned int)f2bf((v.y - mu) * rstd * g4.y + be4.y) << 16);
    unsigned int hi = (unsigned int)f2bf((v.z - mu) * rstd * g4.z + be4.z)
                    | ((unsigned int)f2bf((v.w - mu) * rstd * g4.w + be4.w) << 16);
    *(uint2*)&xs[sl * XS + lane * 4] = make_uint2(lo, hi);
  }
  __syncthreads();

  // phase 2: MFMA projection  o[s][p] = sum_c x[s][c] * W[p][c]; wave w owns rows w*16..+16
  const f32x4 z4 = {0.f, 0.f, 0.f, 0.f};
  f32x4 acc[4];
#pragma unroll
  for (int nt = 0; nt < 4; ++nt) acc[nt] = z4;
  for (int kt = 0; kt < 8; ++kt) {
    const s8v av = *(const s8v*)&xs[(w * 16 + nlo) * XS + kt * 32 + gq * 8];
#pragma unroll
    for (int nt = 0; nt < 4; ++nt) {
      const s8v bv = ((const s8v*)wab)[(nt * 8 + kt) * 64 + lane];
      acc[nt] = __builtin_amdgcn_mfma_f32_16x16x32_bf16(av, bv, acc[nt], 0, 0, 0);
    }
  }
#pragma unroll
  for (int nt = 0; nt < 4; ++nt)
#pragma unroll
    for (int r = 0; r < 4; ++r)
      os[(w * 16 + gq * 4 + r) * OS + nt * 16 + nlo] = acc[nt][r];
  __syncthreads();

  // phase 3: fragment-order transposed write to afrag/bfrag
#pragma unroll
  for (int q = 0; q < 2; ++q) {
    const int set = q * 256 + tid;           // < 512
    const int lf  = set & 63;                // fragment lane
    const int ktl = (set >> 6) & 1;          // local k-tile (32 s each)
    const int hi2 = (set >> 7) & 1;          // c/d half (16)
    const int mat = (set >> 8) & 1;          // 0 = a, 1 = b
    const int g2  = lf >> 4;
    const int p   = mat * 32 + (lf & 15) + 16 * hi2;
    s8v pk;
#pragma unroll
    for (int j = 0; j < 8; ++j) {
      const int srow = ktl * 32 + g2 * 8 + j;
      pk[j] = (short)f2bf(os[srow * OS + p]);
    }
    unsigned short* dst = mat ? bfrag : afrag;
    const int rb = i * 2 + hi2;
    const int kt = sh * 2 + ktl;
    *(s8v*)(dst + ((size_t)((rb * 4 + kt) * 64 + lf)) * 8) = pk;
  }
}

// ---------------- kernel_main: fused outer-product + projection ----------------
// block = 8i x 8j tile; 8 waves (512 thr).
// stage 1: outer[m=(i,c)][n=(j,d)] = sum_s a_t[m][s] b_t[n][s]   (M=N=256, K=128)
// LDS:     t[ij<64][k'=d*32+c <1024] bf16, stride TS, XOR-swizzled, scaled 1/128
// stage 2: out[ij][z] = sum_k' t[ij][k'] * Wp2[z][k'] + bproj[z]
#define TS 1032  // halfword row stride (2064B: 16B-mult, +4-bank/row spread)
__global__ __launch_bounds__(512, 2) void kernel_main(
    const unsigned short* __restrict__ afrag, const unsigned short* __restrict__ bfrag,
    const unsigned short* __restrict__ wfrag, const float* __restrict__ bproj,
    float* __restrict__ out) {
  extern __shared__ unsigned short t[];      // [64][TS]
  const int bid = blockIdx.x;
  const int bi = bid / 48, bj = bid % 48;
  const int tid = threadIdx.x;
  const int wave = tid >> 6, lane = tid & 63;
  const int wm = wave >> 1, wn = wave & 1;   // 4 x 2 wave grid for stage 1
  const int gq = lane >> 4, nlo = lane & 15;

  const f32x4 z4 = {0.f, 0.f, 0.f, 0.f};
  f32x4 acc[4][8];
#pragma unroll
  for (int mt = 0; mt < 4; ++mt)
#pragma unroll
    for (int nt = 0; nt < 8; ++nt) acc[mt][nt] = z4;

  const s8v* ag = (const s8v*)afrag;
  const s8v* bg = (const s8v*)bfrag;
#pragma unroll
  for (int kt = 0; kt < 4; ++kt) {
    s8v av[4], bv[8];
#pragma unroll
    for (int mt = 0; mt < 4; ++mt)
      av[mt] = ag[((bi * 16 + wm * 4 + mt) * 4 + kt) * 64 + lane];
#pragma unroll
    for (int nt = 0; nt < 8; ++nt)
      bv[nt] = bg[((bj * 16 + wn * 8 + nt) * 4 + kt) * 64 + lane];
#pragma unroll
    for (int mt = 0; mt < 4; ++mt)
#pragma unroll
      for (int nt = 0; nt < 8; ++nt)
        acc[mt][nt] = __builtin_amdgcn_mfma_f32_16x16x32_bf16(av[mt], bv[nt], acc[mt][nt], 0, 0, 0);
  }

  // outer -> LDS (bf16, * 1/S), k' = d*32 + c, swizzle: off ^= (d&3)<<3 (halfwords)
#pragma unroll
  for (int mt = 0; mt < 4; ++mt) {
    const int m0 = wm * 64 + mt * 16 + gq * 4;   // row of acc reg r=0
    const int iloc = m0 >> 5;
    const int c0 = m0 & 31;                      // 4-aligned
#pragma unroll
    for (int nt = 0; nt < 8; ++nt) {
      const int n = wn * 128 + nt * 16 + nlo;
      const int jloc = n >> 5, d = n & 31;
      const int ij = iloc * 8 + jloc;
      const unsigned int lo = (unsigned int)f2bf(acc[mt][nt][0] * 0.0078125f)
                            | ((unsigned int)f2bf(acc[mt][nt][1] * 0.0078125f) << 16);
      const unsigned int hi = (unsigned int)f2bf(acc[mt][nt][2] * 0.0078125f)
                            | ((unsigned int)f2bf(acc[mt][nt][3] * 0.0078125f) << 16);
      const int off = (d * 32 + c0) ^ ((d & 3) << 3);
      *(uint2*)&t[ij * TS + off] = make_uint2(lo, hi);
    }
  }
  __syncthreads();

  // stage 2: wave owns z-block = wave*16..+16, all 64 ij rows
  const float bz = bproj[wave * 16 + nlo];
  f32x4 acc2[4];
#pragma unroll
  for (int mt = 0; mt < 4; ++mt) acc2[mt] = z4;
  const s8v* wg = (const s8v*)wfrag;
  for (int kt2 = 0; kt2 < 32; ++kt2) {
    const s8v wv = wg[(wave * 32 + kt2) * 64 + lane];
    const int roff = (kt2 * 32 + gq * 8) ^ ((kt2 & 3) << 3);  // d = kt2 here
#pragma unroll
    for (int mt = 0; mt < 4; ++mt) {
      const s8v av2 = *(const s8v*)&t[(mt * 16 + nlo) * TS + roff];
      acc2[mt] = __builtin_amdgcn_mfma_f32_16x16x32_bf16(av2, wv, acc2[mt], 0, 0, 0);
    }
  }

  const int z = wave * 16 + nlo;
#pragma unroll
  for (int mt = 0; mt < 4; ++mt)
#pragma unroll
    for (int r = 0; r < 4; ++r) {
      const int ijl = mt * 16 + gq * 4 + r;
      const int gi = bi * 8 + (ijl >> 3), gj = bj * 8 + (ijl & 7);
      out[(size_t)(gi * 384 + gj) * 128 + z] = acc2[mt][r] + bz;
    }
}

extern "C" void kernel_launch(void* const* d_in, const int* in_sizes, int n_in,
                              void* d_out, int out_size, void* d_ws, size_t ws_size,
                              hipStream_t stream) {
  const float* msa   = (const float*)d_in[0];
  const float* gam   = (const float*)d_in[1];
  const float* bet   = (const float*)d_in[2];
  const float* Wa    = (const float*)d_in[3];
  const float* Wb    = (const float*)d_in[4];
  const float* Wproj = (const float*)d_in[5];
  const float* bpr   = (const float*)d_in[6];
  float* out = (float*)d_out;

  // workspace layout (bf16 elems): afrag 3MB, bfrag 3MB, wab 32KB, wfrag 256KB
  if (ws_size < 6586368) return;
  unsigned short* afrag = (unsigned short*)d_ws;
  unsigned short* bfrag = afrag + 1572864;
  unsigned short* wab   = bfrag + 1572864;
  unsigned short* wfr   = wab + 16384;

  (void)hipFuncSetAttribute(reinterpret_cast<const void*>(kernel_main),
                            hipFuncAttributeMaxDynamicSharedMemorySize, 64 * TS * 2);

  prep_w_kernel<<<576, 256, 0, stream>>>(Wa, Wb, Wproj, wab, wfr);
  kernel_a<<<768, 256, 0, stream>>>(msa, gam, bet, wab, afrag, bfrag);
  kernel_main<<<2304, 512, 64 * TS * 2, stream>>>(afrag, bfrag, wfr, bpr, out);
}